// Round 1
// baseline (392.301 us; speedup 1.0000x reference)
//
#include <hip/hip_runtime.h>

#define T_STEPS 256
#define F_IN    16
#define HID     8
#define LANES_PER_B 8
#define BLOCK   256
#define B_PER_BLOCK (BLOCK / LANES_PER_B)   // 32

__device__ __forceinline__ float fast_sig(float x) {
    // sigmoid(x) = 1 / (1 + e^-x);  e^-x = 2^(-x*log2e)
    float e = __builtin_amdgcn_exp2f(-1.44269504088896f * x);
    e = fminf(e, 1.0e30f);                       // guard inf -> NaN in Newton
    float d = 1.0f + e;
    float r = __builtin_amdgcn_rcpf(d);
    r = r * (2.0f - d * r);                      // 1 Newton step, ~0.5 ulp
    return r;
}

__device__ __forceinline__ float fast_tanh(float x) {
    // tanh(x) = 2*sigmoid(2x) - 1
    float e = __builtin_amdgcn_exp2f(-2.88539008177793f * x);
    e = fminf(e, 1.0e30f);
    float d = 1.0f + e;
    float r = __builtin_amdgcn_rcpf(d);
    r = r * (2.0f - d * r);
    return 2.0f * r - 1.0f;
}

__global__ __launch_bounds__(BLOCK, 1)
void lstm_fused_kernel(const float* __restrict__ past,   // [B,T,F]
                       const float* __restrict__ fut,    // [B,8]
                       const float* __restrict__ W1,     // [16,32]
                       const float* __restrict__ U1,     // [8,32]
                       const float* __restrict__ b1,     // [32]
                       const float* __restrict__ W2,     // [8,32]
                       const float* __restrict__ U2,     // [8,32]
                       const float* __restrict__ b2,     // [32]
                       const float* __restrict__ Wd1,    // [16,8]
                       const float* __restrict__ bd1,    // [8]
                       const float* __restrict__ Wd2,    // [8,8]
                       const float* __restrict__ bd2,    // [8]
                       const float* __restrict__ Wo,     // [8,4]
                       const float* __restrict__ bo,     // [4]
                       float* __restrict__ out)          // [B,4]
{
    const int tid = threadIdx.x;
    const int j   = tid & (LANES_PER_B - 1);             // owned hidden index
    const int b   = blockIdx.x * B_PER_BLOCK + (tid >> 3);

    // ---- per-lane weight columns in registers ----
    // lane j owns gate columns {j, 8+j, 16+j, 24+j}  (gate order i,f,g,o)
    float w1c[16][4], u1c[8][4], w2c[8][4], u2c[8][4], b1c[4], b2c[4];
#pragma unroll
    for (int g = 0; g < 4; ++g) {
        const int col = g * 8 + j;
        b1c[g] = b1[col];
        b2c[g] = b2[col];
#pragma unroll
        for (int f = 0; f < 16; ++f) w1c[f][g] = W1[f * 32 + col];
#pragma unroll
        for (int k = 0; k < 8; ++k) {
            u1c[k][g] = U1[k * 32 + col];
            w2c[k][g] = W2[k * 32 + col];
            u2c[k][g] = U2[k * 32 + col];
        }
    }

    const float* xrow = past + (size_t)b * (T_STEPS * F_IN);

    float h1 = 0.f, c1 = 0.f, h2 = 0.f, c2 = 0.f;
    float h1all[8], h2all[8];
#pragma unroll
    for (int k = 0; k < 8; ++k) { h1all[k] = 0.f; h2all[k] = 0.f; }

    // software prefetch of x(t=0): the 8 lanes of a batch read the same 64B line
    float4 xn0 = *(const float4*)(xrow + 0);
    float4 xn1 = *(const float4*)(xrow + 4);
    float4 xn2 = *(const float4*)(xrow + 8);
    float4 xn3 = *(const float4*)(xrow + 12);

    for (int t = 0; t < T_STEPS; ++t) {
        float x[16];
        x[0]=xn0.x;  x[1]=xn0.y;  x[2]=xn0.z;  x[3]=xn0.w;
        x[4]=xn1.x;  x[5]=xn1.y;  x[6]=xn1.z;  x[7]=xn1.w;
        x[8]=xn2.x;  x[9]=xn2.y;  x[10]=xn2.z; x[11]=xn2.w;
        x[12]=xn3.x; x[13]=xn3.y; x[14]=xn3.z; x[15]=xn3.w;

        // prefetch next timestep (branchless clamp; dead at t=T-1)
        const int tn = (t + 1 < T_STEPS) ? (t + 1) : t;
        const float* xr = xrow + tn * F_IN;
        xn0 = *(const float4*)(xr + 0);
        xn1 = *(const float4*)(xr + 4);
        xn2 = *(const float4*)(xr + 8);
        xn3 = *(const float4*)(xr + 12);

        // ---- layer 1:  z = x@W1 + b1 + h1@U1 ----
        float a0 = b1c[0], a1 = b1c[1], a2 = b1c[2], a3 = b1c[3];
#pragma unroll
        for (int f = 0; f < 16; ++f) {
            const float xv = x[f];
            a0 = fmaf(xv, w1c[f][0], a0);
            a1 = fmaf(xv, w1c[f][1], a1);
            a2 = fmaf(xv, w1c[f][2], a2);
            a3 = fmaf(xv, w1c[f][3], a3);
        }
#pragma unroll
        for (int k = 0; k < 8; ++k) {
            const float hk = h1all[k];
            a0 = fmaf(hk, u1c[k][0], a0);
            a1 = fmaf(hk, u1c[k][1], a1);
            a2 = fmaf(hk, u1c[k][2], a2);
            a3 = fmaf(hk, u1c[k][3], a3);
        }
        c1 = fast_sig(a1) * c1 + fast_sig(a0) * fast_tanh(a2);
        h1 = fast_sig(a3) * fast_tanh(c1);

        // all-gather h1 across the 8-lane group (layer-2 input at this t)
#pragma unroll
        for (int k = 0; k < 8; ++k) h1all[k] = __shfl(h1, k, LANES_PER_B);

        // ---- layer 2:  z = h1@W2 + b2 + h2@U2 ----
        float d0 = b2c[0], d1v = b2c[1], d2v = b2c[2], d3v = b2c[3];
#pragma unroll
        for (int k = 0; k < 8; ++k) {
            const float hk = h1all[k];
            d0  = fmaf(hk, w2c[k][0], d0);
            d1v = fmaf(hk, w2c[k][1], d1v);
            d2v = fmaf(hk, w2c[k][2], d2v);
            d3v = fmaf(hk, w2c[k][3], d3v);
        }
#pragma unroll
        for (int k = 0; k < 8; ++k) {
            const float hk = h2all[k];
            d0  = fmaf(hk, u2c[k][0], d0);
            d1v = fmaf(hk, u2c[k][1], d1v);
            d2v = fmaf(hk, u2c[k][2], d2v);
            d3v = fmaf(hk, u2c[k][3], d3v);
        }
        c2 = fast_sig(d1v) * c2 + fast_sig(d0) * fast_tanh(d2v);
        h2 = fast_sig(d3v) * fast_tanh(c2);

#pragma unroll
        for (int k = 0; k < 8; ++k) h2all[k] = __shfl(h2, k, LANES_PER_B);
    }

    // ---- head: concat(h2, fut) -> 16 -> relu8 -> relu8 -> 4 ----
    float fm[8];
#pragma unroll
    for (int k = 0; k < 8; ++k) fm[k] = fut[b * 8 + k];

    float s1 = bd1[j];
#pragma unroll
    for (int k = 0; k < 8; ++k) s1 = fmaf(h2all[k], Wd1[k * 8 + j], s1);
#pragma unroll
    for (int k = 0; k < 8; ++k) s1 = fmaf(fm[k], Wd1[(8 + k) * 8 + j], s1);
    s1 = fmaxf(s1, 0.f);

    float d1all[8];
#pragma unroll
    for (int k = 0; k < 8; ++k) d1all[k] = __shfl(s1, k, LANES_PER_B);

    float s2 = bd2[j];
#pragma unroll
    for (int k = 0; k < 8; ++k) s2 = fmaf(d1all[k], Wd2[k * 8 + j], s2);
    s2 = fmaxf(s2, 0.f);

    float d2all[8];
#pragma unroll
    for (int k = 0; k < 8; ++k) d2all[k] = __shfl(s2, k, LANES_PER_B);

    if (j < 4) {
        float so = bo[j];
#pragma unroll
        for (int k = 0; k < 8; ++k) so = fmaf(d2all[k], Wo[k * 4 + j], so);
        out[b * 4 + j] = so;
    }
}

extern "C" void kernel_launch(void* const* d_in, const int* in_sizes, int n_in,
                              void* d_out, int out_size, void* d_ws, size_t ws_size,
                              hipStream_t stream) {
    // inputs: 0 img (unused), 1 past_metadata, 2 future_metadata,
    //         3 W1, 4 U1, 5 b1, 6 W2, 7 U2, 8 b2,
    //         9 Wd1, 10 bd1, 11 Wd2, 12 bd2, 13 Wo, 14 bo
    const float* past = (const float*)d_in[1];
    const float* fut  = (const float*)d_in[2];
    const float* W1   = (const float*)d_in[3];
    const float* U1   = (const float*)d_in[4];
    const float* b1   = (const float*)d_in[5];
    const float* W2   = (const float*)d_in[6];
    const float* U2   = (const float*)d_in[7];
    const float* b2   = (const float*)d_in[8];
    const float* Wd1  = (const float*)d_in[9];
    const float* bd1  = (const float*)d_in[10];
    const float* Wd2  = (const float*)d_in[11];
    const float* bd2  = (const float*)d_in[12];
    const float* Wo   = (const float*)d_in[13];
    const float* bo   = (const float*)d_in[14];
    float* out = (float*)d_out;

    const int B = in_sizes[2] / 8;                 // future_metadata is [B,8]
    const int grid = B / B_PER_BLOCK;              // 8192/32 = 256 blocks

    lstm_fused_kernel<<<grid, BLOCK, 0, stream>>>(
        past, fut, W1, U1, b1, W2, U2, b2,
        Wd1, bd1, Wd2, bd2, Wo, bo, out);
}